// Round 5
// baseline (828.343 us; speedup 1.0000x reference)
//
#include <hip/hip_runtime.h>
#include <hip/hip_fp16.h>

#define BUCKET_BITS 12
#define BUCKET_SIZE 4096           // atoms per bucket -> 16 KB LDS tile in reduce
#define NB 256                     // max buckets (n_atoms <= 1M)
#define PPB 8192                   // pairs per scatter block (32 KB LDS staging)
#define BLK_A 256
#define ITERS (PPB / 4 / BLK_A)    // int4 groups per thread = 8

typedef int      v4i __attribute__((ext_vector_type(4)));
typedef float    v4f __attribute__((ext_vector_type(4)));
typedef unsigned v4u __attribute__((ext_vector_type(4)));

// ---------------- fast path ----------------

__global__ void init_cursors(int* __restrict__ cur, int nbuckets, int cap) {
    int b = blockIdx.x * blockDim.x + threadIdx.x;
    if (b < nbuckets) cur[b] = b * cap;
}

// One global pass: load streams (nontemporal), gather charges (L2-resident),
// pack entries into registers; LDS histogram -> scan -> reserve; pure-LDS
// placement; coalesced flush to per-bucket global regions.
// Entry = (local_atom_idx << 16) | fp16_bits(v)  -- 4 bytes.
__global__ __launch_bounds__(BLK_A, 4) void pair_scatter(
    const v4i*   __restrict__ first4,
    const v4i*   __restrict__ second4,
    const v4f*   __restrict__ dist4,
    const float* __restrict__ charges,
    const float* __restrict__ ecf_p,
    int* __restrict__ cur,
    unsigned* __restrict__ entries,
    int n_pairs4) {
    __shared__ unsigned stag[PPB];
    __shared__ int hist[NB];
    __shared__ int scanA[NB];
    __shared__ int lofs[NB + 1];
    __shared__ int gadj[NB];

    const int tid = threadIdx.x;
    hist[tid] = 0;
    __syncthreads();

    const int base4 = blockIdx.x * (PPB / 4);
    const float ecf = *ecf_p;

    unsigned ev[ITERS * 4];   // packed entries, carried in registers
    unsigned bks[ITERS];      // 4 bucket ids packed per word

    // pass 1: single read of all streams + gather + pack + histogram
    #pragma unroll
    for (int it = 0; it < ITERS; ++it) {
        int g = base4 + it * BLK_A + tid;
        if (g < n_pairs4) {
            v4i f = __builtin_nontemporal_load(&first4[g]);
            v4i s = __builtin_nontemporal_load(&second4[g]);
            v4f d = __builtin_nontemporal_load(&dist4[g]);
            float v0 = ecf * charges[s[0]] / d[0];
            float v1 = ecf * charges[s[1]] / d[1];
            float v2 = ecf * charges[s[2]] / d[2];
            float v3 = ecf * charges[s[3]] / d[3];
            ev[it * 4 + 0] = ((unsigned)(f[0] & (BUCKET_SIZE - 1)) << 16) |
                             (unsigned)__half_as_ushort(__float2half(v0));
            ev[it * 4 + 1] = ((unsigned)(f[1] & (BUCKET_SIZE - 1)) << 16) |
                             (unsigned)__half_as_ushort(__float2half(v1));
            ev[it * 4 + 2] = ((unsigned)(f[2] & (BUCKET_SIZE - 1)) << 16) |
                             (unsigned)__half_as_ushort(__float2half(v2));
            ev[it * 4 + 3] = ((unsigned)(f[3] & (BUCKET_SIZE - 1)) << 16) |
                             (unsigned)__half_as_ushort(__float2half(v3));
            unsigned b0 = (unsigned)f[0] >> BUCKET_BITS;
            unsigned b1 = (unsigned)f[1] >> BUCKET_BITS;
            unsigned b2 = (unsigned)f[2] >> BUCKET_BITS;
            unsigned b3 = (unsigned)f[3] >> BUCKET_BITS;
            bks[it] = b0 | (b1 << 8) | (b2 << 16) | (b3 << 24);
            atomicAdd(&hist[b0], 1);
            atomicAdd(&hist[b1], 1);
            atomicAdd(&hist[b2], 1);
            atomicAdd(&hist[b3], 1);
        }
    }
    __syncthreads();

    // exclusive prefix scan over 256 buckets (Hillis-Steele in LDS)
    scanA[tid] = hist[tid];
    __syncthreads();
    for (int off = 1; off < NB; off <<= 1) {
        int v = scanA[tid];
        if (tid >= off) v += scanA[tid - off];
        __syncthreads();
        scanA[tid] = v;
        __syncthreads();
    }
    if (tid == 0) lofs[0] = 0;
    lofs[tid + 1] = scanA[tid];
    __syncthreads();

    // reserve this block's contiguous range in each bucket's global region
    int cnt = hist[tid];
    if (cnt > 0) gadj[tid] = atomicAdd(&cur[tid], cnt) - lofs[tid];
    hist[tid] = lofs[tid];   // reuse hist as the local placement cursor
    __syncthreads();

    // pass 2: pure-LDS placement, sorted by bucket
    #pragma unroll
    for (int it = 0; it < ITERS; ++it) {
        int g = base4 + it * BLK_A + tid;
        if (g < n_pairs4) {
            #pragma unroll
            for (int j = 0; j < 4; ++j) {
                int b = (bks[it] >> (8 * j)) & 0xFF;
                int p = atomicAdd(&hist[b], 1);
                stag[p] = ev[it * 4 + j];
            }
        }
    }
    __syncthreads();

    // coalesced flush: flat index i -> bucket via binary search in lofs;
    // consecutive i within a bucket run -> consecutive global addresses.
    const int tot = lofs[NB];
    for (int i = tid; i < tot; i += BLK_A) {
        unsigned e = stag[i];
        int lo = 0, hi = NB - 1;
        #pragma unroll
        for (int s = 0; s < 8; ++s) {
            int mid = (lo + hi + 1) >> 1;
            if (lofs[mid] <= i) lo = mid; else hi = mid - 1;
        }
        __builtin_nontemporal_store(e, &entries[gadj[lo] + i]);
    }
}

// One block per bucket: LDS voltage tile + fused per-atom coulomb and
// LDS-privatized molecule partial; dense partial flush (no global atomics).
__global__ __launch_bounds__(1024) void bucket_reduce_fused(
    const unsigned* __restrict__ entries,
    const int* __restrict__ cur,
    const float* __restrict__ charges,
    const int*  __restrict__ mol_index,
    float* __restrict__ voltage,
    float* __restrict__ partials,
    int n_mol, int cap, int n_atoms) {
    __shared__ float volt[BUCKET_SIZE];
    extern __shared__ float molsm[];
    const int b = blockIdx.x;
    for (int i = threadIdx.x; i < BUCKET_SIZE; i += blockDim.x) volt[i] = 0.f;
    for (int i = threadIdx.x; i < n_mol; i += blockDim.x) molsm[i] = 0.f;
    __syncthreads();

    const int start = b * cap;                // cap multiple of 4 -> 16B aligned
    const int cnt = cur[b] - start;
    const int cnt4 = cnt >> 2;
    const v4u* e4p = (const v4u*)(entries + start);
    for (int i = threadIdx.x; i < cnt4; i += blockDim.x) {
        v4u e = __builtin_nontemporal_load(&e4p[i]);
        atomicAdd(&volt[e[0] >> 16], __half2float(__ushort_as_half((unsigned short)(e[0] & 0xFFFFu))));
        atomicAdd(&volt[e[1] >> 16], __half2float(__ushort_as_half((unsigned short)(e[1] & 0xFFFFu))));
        atomicAdd(&volt[e[2] >> 16], __half2float(__ushort_as_half((unsigned short)(e[2] & 0xFFFFu))));
        atomicAdd(&volt[e[3] >> 16], __half2float(__ushort_as_half((unsigned short)(e[3] & 0xFFFFu))));
    }
    for (int i = (cnt4 << 2) + threadIdx.x; i < cnt; i += blockDim.x) {
        unsigned e = entries[start + i];
        atomicAdd(&volt[e >> 16], __half2float(__ushort_as_half((unsigned short)(e & 0xFFFFu))));
    }
    __syncthreads();

    const int abase = b << BUCKET_BITS;
    const int nat = min(BUCKET_SIZE, n_atoms - abase);
    for (int i = threadIdx.x; i < nat; i += blockDim.x) {
        float v = volt[i];
        __builtin_nontemporal_store(v, &voltage[abase + i]);
        float c = 0.5f * v * charges[abase + i];
        atomicAdd(&molsm[mol_index[abase + i]], c);
    }
    __syncthreads();
    float* dst = partials + (size_t)b * n_mol;
    for (int i = threadIdx.x; i < n_mol; i += blockDim.x)
        __builtin_nontemporal_store(molsm[i], &dst[i]);
}

__global__ void mol_final(const float* __restrict__ partials,
                          float* __restrict__ mol_out,
                          int n_mol, int nparts) {
    int m = blockIdx.x * blockDim.x + threadIdx.x;
    if (m >= n_mol) return;
    float s = 0.f;
    for (int p = 0; p < nparts; ++p) s += partials[(size_t)p * n_mol + m];
    mol_out[m] = s;
}

// Unfused bucket_reduce for when partials don't fit in ws.
__global__ __launch_bounds__(1024) void bucket_reduce_plain(
    const unsigned* __restrict__ entries,
    const int* __restrict__ cur,
    float* __restrict__ voltage,
    int cap, int n_atoms) {
    __shared__ float volt[BUCKET_SIZE];
    const int b = blockIdx.x;
    for (int i = threadIdx.x; i < BUCKET_SIZE; i += blockDim.x) volt[i] = 0.f;
    __syncthreads();
    const int start = b * cap;
    const int cnt = cur[b] - start;
    const int cnt4 = cnt >> 2;
    const v4u* e4p = (const v4u*)(entries + start);
    for (int i = threadIdx.x; i < cnt4; i += blockDim.x) {
        v4u e = __builtin_nontemporal_load(&e4p[i]);
        atomicAdd(&volt[e[0] >> 16], __half2float(__ushort_as_half((unsigned short)(e[0] & 0xFFFFu))));
        atomicAdd(&volt[e[1] >> 16], __half2float(__ushort_as_half((unsigned short)(e[1] & 0xFFFFu))));
        atomicAdd(&volt[e[2] >> 16], __half2float(__ushort_as_half((unsigned short)(e[2] & 0xFFFFu))));
        atomicAdd(&volt[e[3] >> 16], __half2float(__ushort_as_half((unsigned short)(e[3] & 0xFFFFu))));
    }
    for (int i = (cnt4 << 2) + threadIdx.x; i < cnt; i += blockDim.x) {
        unsigned e = entries[start + i];
        atomicAdd(&volt[e >> 16], __half2float(__ushort_as_half((unsigned short)(e & 0xFFFFu))));
    }
    __syncthreads();
    const int abase = b << BUCKET_BITS;
    const int nat = min(BUCKET_SIZE, n_atoms - abase);
    for (int i = threadIdx.x; i < nat; i += blockDim.x)
        voltage[abase + i] = volt[i];
}

// ---------------- fallback path (direct atomics, known-correct) ----------------

__global__ void coulomb_pair_direct(const float* __restrict__ dist,
                                    const int*  __restrict__ first,
                                    const int*  __restrict__ second,
                                    const float* __restrict__ charges,
                                    const float* __restrict__ ecf_p,
                                    float* __restrict__ voltage,
                                    int n_pairs) {
    int p = blockIdx.x * blockDim.x + threadIdx.x;
    if (p >= n_pairs) return;
    float v = (*ecf_p) * charges[second[p]] / dist[p];
    atomicAdd(&voltage[first[p]], v);
}

__global__ void coulomb_atom_direct(const float* __restrict__ charges,
                                    const float* __restrict__ voltage,
                                    const int*  __restrict__ mol_index,
                                    float* __restrict__ mol_out,
                                    int n_atoms) {
    int a = blockIdx.x * blockDim.x + threadIdx.x;
    if (a >= n_atoms) return;
    atomicAdd(&mol_out[mol_index[a]], 0.5f * voltage[a] * charges[a]);
}

extern "C" void kernel_launch(void* const* d_in, const int* in_sizes, int n_in,
                              void* d_out, int out_size, void* d_ws, size_t ws_size,
                              hipStream_t stream) {
    const float* charges     = (const float*)d_in[0];
    const float* pair_dist   = (const float*)d_in[1];
    const int*   pair_first  = (const int*)d_in[2];
    const int*   pair_second = (const int*)d_in[3];
    const int*   mol_index   = (const int*)d_in[4];
    const float* ecf_p       = (const float*)d_in[6];

    const int n_atoms = in_sizes[0];
    const int n_pairs = in_sizes[1];
    const int n_mol   = out_size - n_atoms;

    float* mol_out = (float*)d_out;           // [n_mol]
    float* voltage = (float*)d_out + n_mol;   // [n_atoms]

    const int nbuckets = (n_atoms + BUCKET_SIZE - 1) >> BUCKET_BITS;
    long long capll = (long long)n_pairs / (nbuckets > 0 ? nbuckets : 1);
    capll += capll / 16 + 4096;               // >20 sigma headroom for uniform keys
    capll = (capll + 3) & ~3LL;               // 16B-align bucket bases
    long long tot_entries = capll * nbuckets;
    size_t entries_bytes = (size_t)tot_entries * sizeof(unsigned);
    size_t cur_off = (entries_bytes + 255) & ~(size_t)255;
    size_t mol_off = (cur_off + (size_t)nbuckets * sizeof(int) + 255) & ~(size_t)255;
    size_t need_base = cur_off + (size_t)nbuckets * sizeof(int);
    size_t need_mol  = mol_off + (size_t)nbuckets * n_mol * sizeof(float);

    const bool mol_lds_ok = (size_t)n_mol * sizeof(float) <= 40 * 1024;
    const bool fast = (nbuckets >= 1) && (nbuckets <= NB) &&
                      (tot_entries < 0x7fffffffLL) &&
                      ((n_pairs & 3) == 0) &&
                      (need_base <= ws_size);
    const bool mol_fused = fast && mol_lds_ok && (need_mol <= ws_size);

    if (fast) {
        unsigned* entries = (unsigned*)d_ws;
        int* cur = (int*)((char*)d_ws + cur_off);
        const int cap = (int)capll;

        init_cursors<<<(nbuckets + 255) / 256, 256, 0, stream>>>(cur, nbuckets, cap);

        const int n_pairs4 = n_pairs >> 2;
        const int nblocks = (n_pairs + PPB - 1) / PPB;
        pair_scatter<<<nblocks, BLK_A, 0, stream>>>(
            (const v4i*)pair_first, (const v4i*)pair_second,
            (const v4f*)pair_dist, charges, ecf_p, cur, entries, n_pairs4);

        if (mol_fused) {
            float* partials = (float*)((char*)d_ws + mol_off);
            bucket_reduce_fused<<<nbuckets, 1024, n_mol * sizeof(float), stream>>>(
                entries, cur, charges, mol_index, voltage, partials,
                n_mol, cap, n_atoms);
            mol_final<<<(n_mol + 255) / 256, 256, 0, stream>>>(
                partials, mol_out, n_mol, nbuckets);
        } else {
            bucket_reduce_plain<<<nbuckets, 1024, 0, stream>>>(
                entries, cur, voltage, cap, n_atoms);
            hipMemsetAsync(d_out, 0, (size_t)n_mol * sizeof(float), stream);
            coulomb_atom_direct<<<(n_atoms + 255) / 256, 256, 0, stream>>>(
                charges, voltage, mol_index, mol_out, n_atoms);
        }
    } else {
        // fallback: direct global atomics (round-1 behavior)
        hipMemsetAsync(d_out, 0, (size_t)out_size * sizeof(float), stream);
        coulomb_pair_direct<<<(n_pairs + 255) / 256, 256, 0, stream>>>(
            pair_dist, pair_first, pair_second, charges, ecf_p, voltage, n_pairs);
        coulomb_atom_direct<<<(n_atoms + 255) / 256, 256, 0, stream>>>(
            charges, voltage, mol_index, mol_out, n_atoms);
    }
}